// Round 1
// 179.375 us; speedup vs baseline: 1.0042x; 1.0042x over previous
//
#include <hip/hip_runtime.h>

// out(b,l,h) = data(b,l,h) * mask(b,l); B=512, L=512, H=100, C=40.
// mask: aE = aI+aL;  l<aE -> 1-(aE-l)/C;  else l<sL -> 1-(l-aI)/C;  else 0.
//
// Key facts:
//  - mask == 0 exactly when l >= max(aE, sL). With sL ~ U[0,512) that is
//    ~49% of all rows -> SKIP the data read there (must still write zeros,
//    output is poisoned). Cuts read traffic ~105 MB -> ~53 MB.
//  - one block per (b, half): aI/aE/sL are block-uniform -> scalar loads
//    once, not 3 per-lane global loads per float4.
//  - 25 exact iterations/thread (6400/256), unroll 5 for in-thread MLP.
// Streams are touch-once -> nontemporal load/store.

constexpr int kL        = 512;
constexpr int kF4PerRow = 25;                 // H=100 floats = 25 float4
constexpr int kF4PerB   = kL * kF4PerRow;     // 12800 float4 per b
constexpr int kChunkF4  = kF4PerB / 2;        // 6400: half of one b per block
constexpr float kInvC   = 1.0f / 40.0f;

typedef float f32x4 __attribute__((ext_vector_type(4)));

__global__ __launch_bounds__(256, 4) void mask_mul_kernel(
    const f32x4* __restrict__ data,
    const int* __restrict__ a_idx,
    const int* __restrict__ a_len,
    const int* __restrict__ s_len,
    f32x4* __restrict__ out)
{
    const int b     = blockIdx.x >> 1;        // uniform -> SGPR
    const int chunk = blockIdx.x & 1;

    // Block-uniform params: compiler emits scalar loads (b is from blockIdx).
    const int aI = a_idx[b];
    const int aE = aI + a_len[b];
    const int sL = s_len[b];
    const int zs = max(aE, sL);               // rows >= zs are exactly zero

    const int base4 = b * kF4PerB + chunk * kChunkF4; // first float4 of block
    const int l0    = chunk * (kL / 2);               // first row of block

    #pragma unroll 5
    for (int i = threadIdx.x; i < kChunkF4; i += 256) {  // exactly 25 iters
        const int idx4 = base4 + i;
        const int l    = l0 + (int)((unsigned)i / 25u);  // row (magic-mul)

        float m;
        if (l < aE)       m = 1.0f - (float)(aE - l) * kInvC;
        else if (l < sL)  m = 1.0f - (float)(l - aI) * kInvC;
        else              m = 0.0f;

        f32x4 v = {0.0f, 0.0f, 0.0f, 0.0f};
        if (l < zs) {                         // zero rows: no HBM fetch
            v = __builtin_nontemporal_load(&data[idx4]);
            v *= m;
        }
        __builtin_nontemporal_store(v, &out[idx4]);
    }
}

extern "C" void kernel_launch(void* const* d_in, const int* in_sizes, int n_in,
                              void* d_out, int out_size, void* d_ws, size_t ws_size,
                              hipStream_t stream) {
    const float* data = (const float*)d_in[0];
    const int* a_idx  = (const int*)d_in[1];
    const int* a_len  = (const int*)d_in[2];
    const int* s_len  = (const int*)d_in[3];
    float* out        = (float*)d_out;

    const int B = out_size / (kL * 100);      // 512
    const int blocks = B * 2;                 // 1024: one per (b, half)
    const int threads = 256;

    mask_mul_kernel<<<blocks, threads, 0, stream>>>(
        (const f32x4*)data, a_idx, a_len, s_len, (f32x4*)out);
}